// Round 1
// baseline (27.456 us; speedup 1.0000x reference)
//
#include <hip/hip_runtime.h>
#include <math.h>

namespace {

constexpr int BB = 8;
constexpr int NN = 1024;
constexpr int CC = 10;
constexpr float RADIUS = 0.04f;
constexpr float ACCEL_SCALE = 0.02f;
constexpr float MAX_VEL = 0.02f;
constexpr float MAX_POS = 1.0f;
constexpr float EPS = 1e-9f;

// Block = 256 threads. Each block handles (batch b, 32 consecutive i-rows),
// 8 lanes ("subs") per i-row, each sub sweeps 128 j's (strided by 8 so the 8
// subs hit 8 distinct LDS banks; lanes with equal sub broadcast).
__global__ __launch_bounds__(256) void gnca_kernel(
    const float* __restrict__ x,   // (B, N, 10)
    const float* __restrict__ W1,  // (14, 16) row-major
    const float* __restrict__ b1,  // (16,)
    const float* __restrict__ W2,  // (16, 7) row-major
    const float* __restrict__ b2,  // (7,)
    float* __restrict__ out)       // (B, N, 10)
{
    __shared__ float2 pos_s[NN];       // 8 KB
    __shared__ float  typ_s[NN];       // 4 KB
    __shared__ float  feat_s[NN][16];  // 64 KB: x[b,j,:] @ W1x + b1
    __shared__ float  W1_s[14 * 16];   // rows 0..3 = W1e, rows 4..13 = W1x
    __shared__ float  W2_s[16 * 7];
    __shared__ float  b2_s[7];

    const int tid = threadIdx.x;
    const int blk = blockIdx.x;          // 0..255
    const int b = blk >> 5;              // batch index
    const int i_base = (blk & 31) * 32;  // 32 i-rows per block

    // ---- stage weights ----
    if (tid < 224) W1_s[tid] = W1[tid];
    if (tid < 112) W2_s[tid] = W2[tid];
    if (tid < 7)   b2_s[tid] = b2[tid];

    const float* __restrict__ xb = x + (size_t)b * NN * CC;

    // ---- stage positions / types ----
    for (int j = tid; j < NN; j += 256) {
        pos_s[j] = make_float2(xb[j * CC + 0], xb[j * CC + 1]);
        typ_s[j] = xb[j * CC + 4];
    }
    __syncthreads();  // W1_s needed below

    // ---- per-node feature vectors: feat[j][h] = b1[h] + sum_c x[b,j,c]*W1x[c][h] ----
    for (int j = tid; j < NN; j += 256) {
        float xv[10];
#pragma unroll
        for (int c = 0; c < 10; ++c) xv[c] = xb[j * CC + c];
#pragma unroll
        for (int h = 0; h < 16; ++h) {
            float a = b1[h];
#pragma unroll
            for (int c = 0; c < 10; ++c) a += xv[c] * W1_s[(4 + c) * 16 + h];
            feat_s[j][h] = a;
        }
    }
    __syncthreads();

    // ---- main sweep ----
    const int i_local = tid >> 3;   // 0..31
    const int sub     = tid & 7;    // 0..7
    const int i = i_base + i_local;

    const float2 pi = pos_s[i];

    float agg[16];
#pragma unroll
    for (int h = 0; h < 16; ++h) agg[h] = 0.0f;
    float deg = 0.0f;
    float cellnb = 0.0f;

    for (int jj = 0; jj < NN / 8; ++jj) {
        const int j = jj * 8 + sub;
        const float2 pj = pos_s[j];
        const float dx = pj.x - pi.x;            // rel = pos[j] - pos[i]
        const float dy = pj.y - pi.y;
        // exact fp32 (no FMA contraction) to match numpy's boundary decisions:
        const float d2 = __fadd_rn(__fadd_rn(__fmul_rn(dx, dx), __fmul_rn(dy, dy)), EPS);
        const float dist = __fsqrt_rn(d2);
        if (dist < RADIUS && dist > 1e-6f) {     // note: dist >= sqrt(EPS) ~ 3.16e-5 always
            const float tgt = typ_s[j];
            deg += 1.0f;
            cellnb += (tgt > 0.5f) ? 1.0f : 0.0f;
#pragma unroll
            for (int h = 0; h < 16; ++h) {
                const float v = dist * W1_s[h] + dx * W1_s[16 + h] + dy * W1_s[32 + h]
                              + tgt * W1_s[48 + h] + feat_s[j][h];
                agg[h] += fmaxf(v, 0.0f);
            }
        }
    }

    // ---- reduce over the 8 subs (aligned 8-lane groups; xor 1/2/4 stays in-group) ----
#pragma unroll
    for (int m = 1; m < 8; m <<= 1) {
#pragma unroll
        for (int h = 0; h < 16; ++h) agg[h] += __shfl_xor(agg[h], m, 64);
        deg    += __shfl_xor(deg, m, 64);
        cellnb += __shfl_xor(cellnb, m, 64);
    }

    if (sub == 0) {
        const float typ_i = typ_s[i];
        const bool is_cell = typ_i > 0.5f;

        // only out[...,0:2] is ever consumed by the reference
        float o0 = deg * b2_s[0];
        float o1 = deg * b2_s[1];
#pragma unroll
        for (int h = 0; h < 16; ++h) {
            o0 += agg[h] * W2_s[h * 7 + 0];
            o1 += agg[h] * W2_s[h * 7 + 1];
        }
        if (!is_cell) { o0 = 0.0f; o1 = 0.0f; }

        const float vx = xb[i * CC + 2];
        const float vy = xb[i * CC + 3];
        float nvx = vx, nvy = vy;
        float npx = pi.x, npy = pi.y;
        if (is_cell) {
            nvx = fminf(fmaxf(vx + o0 * ACCEL_SCALE, -MAX_VEL), MAX_VEL);
            nvy = fminf(fmaxf(vy + o1 * ACCEL_SCALE, -MAX_VEL), MAX_VEL);
            npx = fminf(fmaxf(pi.x + nvx, -MAX_POS), MAX_POS);
            npy = fminf(fmaxf(pi.y + nvy, -MAX_POS), MAX_POS);
        }

        const bool dead     = is_cell && (deg < (float)3);
        const bool consumed = (!is_cell) && (cellnb >= 1.0f);
        const float keep = (dead || consumed) ? 0.0f : 1.0f;

        float* __restrict__ op = out + ((size_t)b * NN + i) * CC;
        op[0] = npx * keep;
        op[1] = npy * keep;
        op[2] = nvx * keep;
        op[3] = nvy * keep;
#pragma unroll
        for (int c = 4; c < 10; ++c) op[c] = xb[i * CC + c] * keep;
    }
}

}  // namespace

extern "C" void kernel_launch(void* const* d_in, const int* in_sizes, int n_in,
                              void* d_out, int out_size, void* d_ws, size_t ws_size,
                              hipStream_t stream) {
    const float* x  = (const float*)d_in[0];
    const float* W1 = (const float*)d_in[1];
    const float* b1 = (const float*)d_in[2];
    const float* W2 = (const float*)d_in[3];
    const float* b2 = (const float*)d_in[4];
    float* out = (float*)d_out;

    // 256 blocks: 8 batches x 32 i-chunks (32 rows each), 256 threads/block.
    gnca_kernel<<<dim3(BB * 32), dim3(256), 0, stream>>>(x, W1, b1, W2, b2, out);
}